// Round 13
// baseline (116.004 us; speedup 1.0000x reference)
//
#include <hip/hip_runtime.h>
#include <math.h>

typedef _Float16 half8 __attribute__((ext_vector_type(8)));
typedef float floatx4 __attribute__((ext_vector_type(4)));

#define HDIM 256
#define NC 15        // value + 4 grad + 10 hess
#define NCP 16       // comps padded to 16 (comp 15 = garbage, never read)
#define SPB 8        // samples per group
#define GPT 2        // groups per team -> 32 samples/block
#define MR 128       // M rows per group = NCP * SPB
#define NWAVE 4      // waves per team
#define NT 4         // n-tiles per wave (64 neurons)

// Row mapping: m = 16*(c>>1) + 4*(sl>>1) + 2*(sl&1) + (c&1).
// LDS: st[2][128][256] f16 = 128KB + part 16KB -> 144KB/WG. XOR swizzle
//    phys_chunk = logical_chunk ^ (m&31).
//
// Ladder (measured):
//  R0 73 | R1 91 (occupancy null) | R2 64 (tail split) | R4 170 (atomics:NEVER)
//  R5 116 (dual-acc spill) | R6 69 (reg-cap spill) | R8 59.5 (bf/af prefetch)
//  R9 59.5 (af[8] NULL) | R10 54.9 (wave-team pairing) | R11 52.5 (GPT=2)
//  R12 51.0 (setprio on role-split: +3%, matches T5 low end).
//  R12 accounting: MFMA-busy 13.8us == hw floor; VALU-busy 17.9us =
//    ~2.6K VALU instr/wave, of which init_acc = 512 (20%!). bench-mlp gap
//    ~60us is harness dispatch-train overhead (R0-vs-R2 delta bounds
//    einstein_k at ~2us) - not addressable.
//  R13 (this): (1) zero-init acc via ks=0 MFMA literal-zero C (kills 512
//    v_accvgpr_write/wave); bias folded into transform/epilogue pre[0]+=b[j];
//    (2) skip c=15 padding comp stores (A-rows feed only never-read C rows);
//    (3) setprio(1) widened to cover af ds_reads (GEMM wave wins LDS pipe
//    vs paired team's transform writes).

__device__ __forceinline__ float ftanh(float x) {
    float e = __expf(2.f * x);
    return fmaf(-2.f, __builtin_amdgcn_rcpf(e + 1.f), 1.f);
}

// ---------------------------------------------------------------------------
// Per-sample analytic Einstein tensor from (f, grad f, hess f). One lane.
// ---------------------------------------------------------------------------
__device__ __forceinline__ void einstein_tail(
    float f, const float* Gf, const float* Hs, float r, float th,
    float* __restrict__ outp)
{
    float Hf[4][4];
    {
        int qq = 0;
#pragma unroll
        for (int k = 0; k < 4; ++k)
#pragma unroll
            for (int l = k; l < 4; ++l) { Hf[k][l] = Hs[qq]; Hf[l][k] = Hs[qq]; ++qq; }
    }
    float sn = sinf(th), cs = cosf(th);
    float E  = expf(f);

    float gd[4] = {-1.f, E, r * r, r * r * sn * sn};
    float gi[4];
#pragma unroll
    for (int a = 0; a < 4; ++a) gi[a] = 1.f / gd[a];

    float dgv[4][4];
    float ddg[4][4][4];
#pragma unroll
    for (int a = 0; a < 4; ++a)
#pragma unroll
        for (int k = 0; k < 4; ++k) {
            dgv[a][k] = 0.f;
#pragma unroll
            for (int l = 0; l < 4; ++l) ddg[a][k][l] = 0.f;
        }
#pragma unroll
    for (int k = 0; k < 4; ++k) dgv[1][k] = E * Gf[k];
    dgv[2][1] = 2.f * r;
    dgv[3][1] = 2.f * r * sn * sn;
    dgv[3][2] = 2.f * r * r * sn * cs;
#pragma unroll
    for (int k = 0; k < 4; ++k)
#pragma unroll
        for (int l = 0; l < 4; ++l)
            ddg[1][k][l] = E * fmaf(Gf[k], Gf[l], Hf[k][l]);
    ddg[2][1][1] = 2.f;
    ddg[3][1][1] = 2.f * sn * sn;
    ddg[3][1][2] = 4.f * r * sn * cs;
    ddg[3][2][1] = 4.f * r * sn * cs;
    ddg[3][2][2] = 2.f * r * r * (cs * cs - sn * sn);

    auto SYMF = [&](int a, int i, int jx) -> float {
        float sy = 0.f;
        if (a == i)  sy += dgv[a][jx];
        if (a == jx) sy += dgv[a][i];
        if (i == jx) sy -= dgv[i][a];
        return sy;
    };
    auto DF = [&](int a, int i, int jx, int k) -> float {
        float ds = 0.f;
        if (a == i)  ds += ddg[a][jx][k];
        if (a == jx) ds += ddg[a][i][k];
        if (i == jx) ds -= ddg[i][a][k];
        return 0.5f * (gi[a] * ds - gi[a] * gi[a] * dgv[a][k] * SYMF(a, i, jx));
    };

    float Gm[4][4][4];
#pragma unroll
    for (int a = 0; a < 4; ++a)
#pragma unroll
        for (int i = 0; i < 4; ++i)
#pragma unroll
            for (int jx = 0; jx < 4; ++jx)
                Gm[a][i][jx] = 0.5f * gi[a] * SYMF(a, i, jx);

    float ric[4][4];
#pragma unroll
    for (int b = 0; b < 4; ++b)
#pragma unroll
        for (int d = 0; d < 4; ++d) {
            float sum = 0.f;
#pragma unroll
            for (int a = 0; a < 4; ++a) {
                sum += DF(a, d, b, a) - DF(a, a, b, d);
#pragma unroll
                for (int e = 0; e < 4; ++e)
                    sum += Gm[a][a][e] * Gm[e][d][b] - Gm[a][d][e] * Gm[e][a][b];
            }
            ric[b][d] = sum;
        }

    float Rs = 0.f;
#pragma unroll
    for (int b = 0; b < 4; ++b) Rs += gi[b] * ric[b][b];

#pragma unroll
    for (int a = 0; a < 4; ++a)
#pragma unroll
        for (int b = 0; b < 4; ++b) {
            float v = gi[a] * gi[b] * ric[a][b];
            if (a == b) v -= 0.5f * gi[a] * Rs;
            outp[a * 4 + b] = v;
        }
}

// ---------------------------------------------------------------------------
// Standalone tail kernel: 1 sample per lane, in place on io (= out buffer).
// ---------------------------------------------------------------------------
__global__ __launch_bounds__(64) void einstein_k(
    const float* __restrict__ coords, const float* __restrict__ bo,
    float* io, int B)
{
    const int s = blockIdx.x * 64 + threadIdx.x;
    if (s >= B) return;
    float4 f0 = *(const float4*)&io[s * 16 + 0];
    float4 f1 = *(const float4*)&io[s * 16 + 4];
    float4 f2 = *(const float4*)&io[s * 16 + 8];
    float4 f3 = *(const float4*)&io[s * 16 + 12];
    float f = f0.x + bo[0];
    float Gf[4] = {f0.y, f0.z, f0.w, f1.x};
    float Hs[10] = {f1.y, f1.z, f1.w, f2.x, f2.y, f2.z, f2.w, f3.x, f3.y, f3.z};
    float r  = coords[s * 4 + 1];
    float th = coords[s * 4 + 2];
    float res[16];
    einstein_tail(f, Gf, Hs, r, th, res);
#pragma unroll
    for (int e = 0; e < 4; ++e)
        *(float4*)&io[s * 16 + e * 4] =
            make_float4(res[e*4+0], res[e*4+1], res[e*4+2], res[e*4+3]);
}

// ---------------------------------------------------------------------------
// Coalesced 64x64 LDS-tile transpose: Wt[m][j*256+k] = (f16)W_m[k*256+j].
// ---------------------------------------------------------------------------
__global__ __launch_bounds__(256) void pack_wt(
    const float* __restrict__ W2, const float* __restrict__ W3,
    _Float16* __restrict__ Wt)
{
    __shared__ float t[64][65];
    const int m    = blockIdx.x >> 4;
    const float* W = m ? W3 : W2;
    const int tile = blockIdx.x & 15;
    const int k0 = (tile >> 2) * 64, j0 = (tile & 3) * 64;
    const int tx = threadIdx.x & 63, ty = threadIdx.x >> 6;   // 64 x 4
#pragma unroll
    for (int i = 0; i < 16; ++i) {
        int k = ty + i * 4;
        t[k][tx] = W[(k0 + k) * HDIM + j0 + tx];              // coalesced read
    }
    __syncthreads();
#pragma unroll
    for (int i = 0; i < 16; ++i) {
        int jj = ty + i * 4;
        Wt[(size_t)m * HDIM * HDIM + (j0 + jj) * HDIM + k0 + tx] =
            (_Float16)t[tx][jj];                              // coalesced write
    }
}

// ---------------------------------------------------------------------------
// Wave-team pipelined fused kernel, 2 groups per team. Block = 512 thr =
// 2 teams x 4 waves, 32 samples. Grid = B/32 = 256 = exactly 1 block/CU.
// LDS 144KB. (512,2) -> 256 unified regs/wave cap.
// ---------------------------------------------------------------------------
template <bool TW>
__global__ __launch_bounds__(512, 2) void mlp_fused(
    const float* __restrict__ coords,
    const float* __restrict__ W1, const float* __restrict__ b1,
    const float* __restrict__ W2, const float* __restrict__ b2,
    const float* __restrict__ W3, const float* __restrict__ b3,
    const float* __restrict__ Wo,
    const _Float16* __restrict__ Wt,   // packed f16 W2^T | W3^T (TW only)
    float* __restrict__ out, int B)    // receives (f,grad,hess); tail adds bo
{
    __shared__ __align__(16) _Float16 st[2][MR * HDIM];      // 131,072 B
    __shared__ float part[2][GPT][NWAVE][SPB][NCP];          //  16,384 B

    const int tid  = threadIdx.x;
    const int team = tid >> 8;       // 0: waves 0-3, 1: waves 4-7
    const int ttid = tid & 255;      // tid within team
    const int w    = ttid >> 6;      // wave-in-team 0..3
    const int lane = tid & 63;
    const int col  = lane & 15;
    const int q    = lane >> 4;
    const int s0   = blockIdx.x * (2 * GPT * SPB);

    _Float16* __restrict__ stT = st[team];

    floatx4 acc[8][NT];              // 128 unified regs (AGPR side)

    auto f4get = [](const float4& v, int i) -> float {
        switch (i & 3) { case 0: return v.x; case 1: return v.y;
                         case 2: return v.z; default: return v.w; }
    };

    auto sbase = [&](int g) { return s0 + (team * GPT + g) * SPB; };

    // ---- layer-1 producer: team-thread = (sample sl, chunk tc of 8 cols) --
    // c = 15 (padding comp) is never stored: its A-rows feed only C rows of
    // comp 15, which no downstream phase reads. Garbage there is harmless.
    auto produce1 = [&](int g) {
        const int sl = ttid & 7;
        const int tc = ttid >> 3;              // 0..31
        int ss = sbase(g) + sl; if (ss >= B) ss = B - 1;
        const float x0 = coords[ss * 4 + 0];
        const float x1 = coords[ss * 4 + 1];
        const float x2 = coords[ss * 4 + 2];
        const float x3 = coords[ss * 4 + 3];
        const int jg = tc * 8;
        float4 wa[4][2];
#pragma unroll
        for (int k = 0; k < 4; ++k) {
            wa[k][0] = *(const float4*)&W1[k * HDIM + jg];
            wa[k][1] = *(const float4*)&W1[k * HDIM + jg + 4];
        }
        float4 bb0 = *(const float4*)&b1[jg];
        float4 bb1 = *(const float4*)&b1[jg + 4];
        half8 ch[NC];
#pragma unroll
        for (int jj = 0; jj < 8; ++jj) {
            const int h = jj >> 2;
            float w0 = f4get(wa[0][h], jj), w1 = f4get(wa[1][h], jj);
            float w2v = f4get(wa[2][h], jj), w3v = f4get(wa[3][h], jj);
            float a = f4get(h ? bb1 : bb0, jj);
            a = fmaf(x0, w0, a); a = fmaf(x1, w1, a);
            a = fmaf(x2, w2v, a); a = fmaf(x3, w3v, a);
            float v = ftanh(a), tp = 1.f - v * v, m2 = -2.f * v * tp;
            float g4[4] = {w0, w1, w2v, w3v};
            ch[0][jj] = (_Float16)v;
#pragma unroll
            for (int k = 0; k < 4; ++k) ch[1 + k][jj] = (_Float16)(tp * g4[k]);
            int idx = 5;
#pragma unroll
            for (int aa = 0; aa < 4; ++aa)
#pragma unroll
                for (int bb2 = aa; bb2 < 4; ++bb2) {
                    ch[idx][jj] = (_Float16)(m2 * g4[aa] * g4[bb2]); ++idx;
                }
        }
#pragma unroll
        for (int c = 0; c < NC; ++c) {
            const int m = 16 * (c >> 1) + 4 * (sl >> 1) + 2 * (sl & 1) + (c & 1);
            const int addr = m * HDIM + (((tc ^ m) & 31) << 3);
            *(half8*)&stT[addr] = ch[c];
        }
    };

    // full-K GEMM: bf 2-deep register double-buffer; af all-8 upfront (R9);
    // ks=0 MFMAs take a literal-zero C (no acc zero-init pass); setprio(1)
    // covers af reads + MFMA burst (T5, role-split structure).
    auto gemm_full = [&](const float* __restrict__ W, int layer) {
        half8 bf[2][NT];
#pragma unroll
        for (int nt = 0; nt < NT; ++nt) {       // prefetch ks = 0
            const int j = w * 64 + nt * 16 + col;
            if constexpr (TW) {
                bf[0][nt] = *(const half8*)&Wt[((size_t)layer * HDIM + j) * HDIM + q * 8];
            } else {
#pragma unroll
                for (int i = 0; i < 8; ++i)
                    bf[0][nt][i] = (_Float16)W[(q * 8 + i) * HDIM + j];
            }
        }
        const floatx4 z = {0.f, 0.f, 0.f, 0.f};
#pragma unroll
        for (int ks = 0; ks < 8; ++ks) {
            const int cur = ks & 1, nxt = cur ^ 1;
            if (ks < 7) {                        // issue ks+1 global loads early
                const int kg2 = (ks + 1) * 32 + q * 8;
#pragma unroll
                for (int nt = 0; nt < NT; ++nt) {
                    const int j = w * 64 + nt * 16 + col;
                    if constexpr (TW) {
                        bf[nxt][nt] = *(const half8*)&Wt[((size_t)layer * HDIM + j) * HDIM + kg2];
                    } else {
#pragma unroll
                        for (int i = 0; i < 8; ++i)
                            bf[nxt][nt][i] = (_Float16)W[(kg2 + i) * HDIM + j];
                    }
                }
            }
            const int lc = ks * 4 + q;           // logical chunk
            __builtin_amdgcn_s_setprio(1);
            half8 af[8];
#pragma unroll
            for (int mt = 0; mt < 8; ++mt) {     // all A-fragments upfront
                const int m = 16 * mt + col;
                af[mt] = *(const half8*)&stT[m * HDIM + (((lc ^ m) & 31) << 3)];
            }
#pragma unroll
            for (int mt = 0; mt < 8; ++mt)
#pragma unroll
                for (int nt = 0; nt < NT; ++nt)
                    acc[mt][nt] = __builtin_amdgcn_mfma_f32_16x16x32_f16(
                        af[mt], bf[cur][nt], (ks == 0) ? z : acc[mt][nt], 0, 0, 0);
            __builtin_amdgcn_s_setprio(0);
        }
    };

    // tanh chain rule + immediate LDS store (register-local, no hold).
    // Bias b[j] (layer-2 bias) is added here (acc no longer carries it).
    auto transform_store = [&](const float* __restrict__ b) {
#pragma unroll
        for (int nt = 0; nt < NT; ++nt) {
            const int j = w * 64 + nt * 16 + col;
            const int jc = j >> 3, jb = j & 7;
            const float bj = b[j];
#pragma unroll
            for (int sv = 0; sv < 2; ++sv) {           // sample-local
                float pre[NCP];
#pragma unroll
                for (int c = 0; c < NCP; ++c)
                    pre[c] = acc[c >> 1][nt][sv * 2 + (c & 1)];
                pre[0] += bj;
                float v = ftanh(pre[0]), tp = 1.f - v * v, m2 = -2.f * v * tp;
                float g4[4] = {pre[1], pre[2], pre[3], pre[4]};
                float ns[NC];
                ns[0] = v;
#pragma unroll
                for (int k = 0; k < 4; ++k) ns[1 + k] = tp * g4[k];
                int idx = 5;
#pragma unroll
                for (int aa = 0; aa < 4; ++aa)
#pragma unroll
                    for (int bb2 = aa; bb2 < 4; ++bb2) {
                        ns[idx] = fmaf(tp, pre[idx], m2 * g4[aa] * g4[bb2]); ++idx;
                    }
#pragma unroll
                for (int c = 0; c < NC; ++c) {
                    const int m = 16 * (c >> 1) + 4 * q + 2 * sv + (c & 1);
                    stT[m * HDIM + (((jc ^ m) & 31) << 3) + jb] = (_Float16)ns[c];
                }
            }
        }
    };

    // layer-3 tanh chain (bias b3 added here) + Wo dot; shfl-reduce over 16
    // cols; partials -> part[team][g]
    auto epilogue_part = [&](int g, const float* __restrict__ b) {
        float wo[NT];
#pragma unroll
        for (int nt = 0; nt < NT; ++nt) wo[nt] = Wo[w * 64 + nt * 16 + col];

        float on2[2][NC];
#pragma unroll
        for (int sv = 0; sv < 2; ++sv)
#pragma unroll
            for (int c = 0; c < NC; ++c) on2[sv][c] = 0.f;
#pragma unroll
        for (int nt = 0; nt < NT; ++nt) {
            const float bj = b[w * 64 + nt * 16 + col];
#pragma unroll
            for (int sv = 0; sv < 2; ++sv) {
                float pre[NCP];
#pragma unroll
                for (int c = 0; c < NCP; ++c)
                    pre[c] = acc[c >> 1][nt][sv * 2 + (c & 1)];
                pre[0] += bj;
                float v = ftanh(pre[0]), tp = 1.f - v * v, m2 = -2.f * v * tp;
                float g4[4] = {pre[1], pre[2], pre[3], pre[4]};
                on2[sv][0] = fmaf(wo[nt], v, on2[sv][0]);
#pragma unroll
                for (int k = 0; k < 4; ++k)
                    on2[sv][1 + k] = fmaf(wo[nt], tp * g4[k], on2[sv][1 + k]);
                int idx = 5;
#pragma unroll
                for (int aa = 0; aa < 4; ++aa)
#pragma unroll
                    for (int bb2 = aa; bb2 < 4; ++bb2) {
                        on2[sv][idx] = fmaf(wo[nt],
                            fmaf(tp, pre[idx], m2 * g4[aa] * g4[bb2]), on2[sv][idx]);
                        ++idx;
                    }
            }
        }
#pragma unroll
        for (int mask = 1; mask < 16; mask <<= 1)
#pragma unroll
            for (int sv = 0; sv < 2; ++sv)
#pragma unroll
                for (int c = 0; c < NC; ++c)
                    on2[sv][c] += __shfl_xor(on2[sv][c], mask, 64);
        if (col == 0) {
#pragma unroll
            for (int sv = 0; sv < 2; ++sv)
#pragma unroll
                for (int c = 0; c < NC; ++c)
                    part[team][g][w][2 * q + sv][c] = on2[sv][c];
        }
    };

    auto final_reduce = [&]() {
        if (ttid < SPB * NC) {        // 120 threads of this team
            const int sl = ttid / NC, c = ttid % NC;
#pragma unroll
            for (int g = 0; g < GPT; ++g) {
                float v = 0.f;
#pragma unroll
                for (int ww = 0; ww < NWAVE; ++ww)
                    v += part[team][g][ww][sl][c];
                int s = sbase(g) + sl;
                if (s < B) out[s * 16 + c] = v;   // bo added in einstein_k
            }
        }
    };

    // ======== 11-slot 2-team x 2-group pipeline (G always paired w/ VALU) ==
    if (team == 0) produce1(0);                                       // S0
    __syncthreads();
    if (team == 0) gemm_full(W2, 0);                                  // S1
    else produce1(0);
    __syncthreads();
    if (team == 0) transform_store(b2);                               // S2
    else gemm_full(W2, 0);
    __syncthreads();
    if (team == 0) gemm_full(W3, 1);                                  // S3
    else transform_store(b2);
    __syncthreads();
    if (team == 0) { epilogue_part(0, b3); produce1(1); }             // S4
    else gemm_full(W3, 1);
    __syncthreads();
    if (team == 0) gemm_full(W2, 0);                                  // S5
    else { epilogue_part(0, b3); produce1(1); }
    __syncthreads();
    if (team == 0) transform_store(b2);                               // S6
    else gemm_full(W2, 0);
    __syncthreads();
    if (team == 0) gemm_full(W3, 1);                                  // S7
    else transform_store(b2);
    __syncthreads();
    if (team == 0) epilogue_part(1, b3);                              // S8
    else gemm_full(W3, 1);
    __syncthreads();
    if (team == 0) final_reduce();                                    // S9
    else epilogue_part(1, b3);
    __syncthreads();
    if (team == 1) final_reduce();                                    // S10
}

extern "C" void kernel_launch(void* const* d_in, const int* in_sizes, int n_in,
                              void* d_out, int out_size, void* d_ws, size_t ws_size,
                              hipStream_t stream) {
    const float* coords = (const float*)d_in[0];
    const float* W1 = (const float*)d_in[1];
    const float* b1 = (const float*)d_in[2];
    const float* W2 = (const float*)d_in[3];
    const float* b2 = (const float*)d_in[4];
    const float* W3 = (const float*)d_in[5];
    const float* b3 = (const float*)d_in[6];
    const float* Wo = (const float*)d_in[7];
    const float* bo = (const float*)d_in[8];
    float* out = (float*)d_out;
    const int B = in_sizes[0] / 4;
    const int spb_blk = 2 * GPT * SPB;                 // 32 samples/block
    const int nblocks = (B + spb_blk - 1) / spb_blk;   // 256 for B=8192

    const size_t wt_bytes = (size_t)2 * HDIM * HDIM * sizeof(_Float16);
    if (ws_size >= wt_bytes) {
        _Float16* Wt = (_Float16*)d_ws;
        pack_wt<<<32, 256, 0, stream>>>(W2, W3, Wt);
        mlp_fused<true><<<nblocks, 512, 0, stream>>>(
            coords, W1, b1, W2, b2, W3, b3, Wo, Wt, out, B);
    } else {
        mlp_fused<false><<<nblocks, 512, 0, stream>>>(
            coords, W1, b1, W2, b2, W3, b3, Wo, nullptr, out, B);
    }
    // out holds (f, grad, hess); transform in place into the Einstein tensor.
    einstein_k<<<(B + 63) / 64, 64, 0, stream>>>(coords, bo, out, B);
}